// Round 10
// baseline (380.879 us; speedup 1.0000x reference)
//
#include <hip/hip_runtime.h>

typedef __attribute__((ext_vector_type(8))) __bf16 bf16x8;
typedef __attribute__((ext_vector_type(4))) float f32x4;

#define B_ROWS 8192
#define D_DIM  1024
#define K_DIM  2048
#define NG     5120

typedef const __attribute__((address_space(1))) void cg_void;
typedef __attribute__((address_space(3))) void lds_void;

__device__ __forceinline__ float bf2f(unsigned short u) {
    union { unsigned int ui; float f; } c; c.ui = ((unsigned int)u) << 16; return c.f;
}
__device__ __forceinline__ unsigned short f2bf(float f) {
    unsigned int u = __float_as_uint(f);
    unsigned int r = u + 0x7fffu + ((u >> 16) & 1u);
    return (unsigned short)(r >> 16);
}
__device__ __forceinline__ float sigm(float v) { return 1.0f / (1.0f + __expf(-v)); }

// ---------------- prep: LN1 (blocks 0..8191) + weight cvt (blocks 8192..20479) ----------------
__global__ __launch_bounds__(256) void prep_kernel(const float* __restrict__ x, const float* __restrict__ h,
                                                   const float* __restrict__ w, const float* __restrict__ b,
                                                   unsigned short* __restrict__ outln,
                                                   const float* __restrict__ wg, const float* __restrict__ wu,
                                                   unsigned short* __restrict__ og, unsigned short* __restrict__ ou) {
    const int bid = blockIdx.x;
    const int t = threadIdx.x;
    if (bid < 8192) {
        const int row = bid;
        const float4 xv = reinterpret_cast<const float4*>(x + (size_t)row * D_DIM)[t];
        const float4 hv = reinterpret_cast<const float4*>(h + (size_t)row * D_DIM)[t];
        float s  = xv.x + xv.y + xv.z + xv.w + hv.x + hv.y + hv.z + hv.w;
        float s2 = xv.x*xv.x + xv.y*xv.y + xv.z*xv.z + xv.w*xv.w
                 + hv.x*hv.x + hv.y*hv.y + hv.z*hv.z + hv.w*hv.w;
#pragma unroll
        for (int off = 32; off > 0; off >>= 1) { s += __shfl_xor(s, off); s2 += __shfl_xor(s2, off); }
        __shared__ float red[8];
        const int wid = t >> 6, lane = t & 63;
        if (lane == 0) { red[wid] = s; red[4 + wid] = s2; }
        __syncthreads();
        s  = red[0] + red[1] + red[2] + red[3];
        s2 = red[4] + red[5] + red[6] + red[7];
        const float mu  = s * (1.0f / K_DIM);
        const float var = s2 * (1.0f / K_DIM) - mu * mu;
        const float inv = rsqrtf(var + 1e-5f);
        const float4 w0 = reinterpret_cast<const float4*>(w)[t];
        const float4 b0 = reinterpret_cast<const float4*>(b)[t];
        const float4 w1 = reinterpret_cast<const float4*>(w + D_DIM)[t];
        const float4 b1 = reinterpret_cast<const float4*>(b + D_DIM)[t];
        ushort4 o0, o1;
        o0.x = f2bf((xv.x - mu) * inv * w0.x + b0.x);
        o0.y = f2bf((xv.y - mu) * inv * w0.y + b0.y);
        o0.z = f2bf((xv.z - mu) * inv * w0.z + b0.z);
        o0.w = f2bf((xv.w - mu) * inv * w0.w + b0.w);
        o1.x = f2bf((hv.x - mu) * inv * w1.x + b1.x);
        o1.y = f2bf((hv.y - mu) * inv * w1.y + b1.y);
        o1.z = f2bf((hv.z - mu) * inv * w1.z + b1.z);
        o1.w = f2bf((hv.w - mu) * inv * w1.w + b1.w);
        reinterpret_cast<ushort4*>(outln + (size_t)row * K_DIM)[t] = o0;
        reinterpret_cast<ushort4*>(outln + (size_t)row * K_DIM + D_DIM)[t] = o1;
    } else {
        const int NG4 = 5120 * 2048 / 4;
        const int NU4 = 1024 * 2048 / 4;
        const int i = (bid - 8192) * 256 + t;
        if (i < NG4) {
            float4 v = reinterpret_cast<const float4*>(wg)[i];
            ushort4 o; o.x = f2bf(v.x); o.y = f2bf(v.y); o.z = f2bf(v.z); o.w = f2bf(v.w);
            reinterpret_cast<ushort4*>(og)[i] = o;
        } else if (i < NG4 + NU4) {
            int j = i - NG4;
            float4 v = reinterpret_cast<const float4*>(wu)[j];
            ushort4 o; o.x = f2bf(v.x); o.y = f2bf(v.y); o.z = f2bf(v.z); o.w = f2bf(v.w);
            reinterpret_cast<ushort4*>(ou)[j] = o;
        }
    }
}

// ---------------- gate sigmoid + LN2 -> bf16 inp2 ----------------
__global__ __launch_bounds__(256) void gate_ln2_kernel(const float* __restrict__ x, const float* __restrict__ h,
                                                       const unsigned short* __restrict__ gates,
                                                       const float* __restrict__ w, const float* __restrict__ b,
                                                       unsigned short* __restrict__ out) {
    const int row = blockIdx.x;
    const int t = threadIdx.x;
    const float4 xv = reinterpret_cast<const float4*>(x + (size_t)row * D_DIM)[t];
    const float4 hv = reinterpret_cast<const float4*>(h + (size_t)row * D_DIM)[t];
    const ushort4 g0v = reinterpret_cast<const ushort4*>(gates + (size_t)row * NG)[t];
    const ushort4 g1v = reinterpret_cast<const ushort4*>(gates + (size_t)row * NG + D_DIM)[t];
    float a0 = xv.x * sigm(bf2f(g0v.x));
    float a1 = xv.y * sigm(bf2f(g0v.y));
    float a2 = xv.z * sigm(bf2f(g0v.z));
    float a3 = xv.w * sigm(bf2f(g0v.w));
    float c0 = hv.x * sigm(bf2f(g1v.x));
    float c1 = hv.y * sigm(bf2f(g1v.y));
    float c2 = hv.z * sigm(bf2f(g1v.z));
    float c3 = hv.w * sigm(bf2f(g1v.w));
    float s  = a0 + a1 + a2 + a3 + c0 + c1 + c2 + c3;
    float s2 = a0*a0 + a1*a1 + a2*a2 + a3*a3 + c0*c0 + c1*c1 + c2*c2 + c3*c3;
#pragma unroll
    for (int off = 32; off > 0; off >>= 1) { s += __shfl_xor(s, off); s2 += __shfl_xor(s2, off); }
    __shared__ float red[8];
    const int wid = t >> 6, lane = t & 63;
    if (lane == 0) { red[wid] = s; red[4 + wid] = s2; }
    __syncthreads();
    s  = red[0] + red[1] + red[2] + red[3];
    s2 = red[4] + red[5] + red[6] + red[7];
    const float mu  = s * (1.0f / K_DIM);
    const float var = s2 * (1.0f / K_DIM) - mu * mu;
    const float inv = rsqrtf(var + 1e-5f);
    const float4 w0 = reinterpret_cast<const float4*>(w)[t];
    const float4 b0 = reinterpret_cast<const float4*>(b)[t];
    const float4 w1 = reinterpret_cast<const float4*>(w + D_DIM)[t];
    const float4 b1 = reinterpret_cast<const float4*>(b + D_DIM)[t];
    ushort4 o0, o1;
    o0.x = f2bf((a0 - mu) * inv * w0.x + b0.x);
    o0.y = f2bf((a1 - mu) * inv * w0.y + b0.y);
    o0.z = f2bf((a2 - mu) * inv * w0.z + b0.z);
    o0.w = f2bf((a3 - mu) * inv * w0.w + b0.w);
    o1.x = f2bf((c0 - mu) * inv * w1.x + b1.x);
    o1.y = f2bf((c1 - mu) * inv * w1.y + b1.y);
    o1.z = f2bf((c2 - mu) * inv * w1.z + b1.z);
    o1.w = f2bf((c3 - mu) * inv * w1.w + b1.w);
    reinterpret_cast<ushort4*>(out + (size_t)row * K_DIM)[t] = o0;
    reinterpret_cast<ushort4*>(out + (size_t)row * K_DIM + D_DIM)[t] = o1;
}

// ---------------- GEMM1: uniform-round grid (768 blocks), R8-verified ----------------
#define PH(BUF, H, KQ, LOADB, STAGE_CODE, VMCNT_CODE) do {                                            \
    bf16x8 aF[4];                                                                                     \
    _Pragma("unroll")                                                                                 \
    for (int m = 0; m < 4; ++m)                                                                       \
        aF[m] = *reinterpret_cast<const bf16x8*>(                                                     \
            &smem[((BUF) * 2 + (H)) * 8192 + ((aRdS[m] ^ ((KQ) * 64)) >> 1)]);                        \
    if (LOADB) {                                                                                      \
        _Pragma("unroll")                                                                             \
        for (int n = 0; n < 4; ++n)                                                                   \
            bF[KQ][n] = *reinterpret_cast<const bf16x8*>(                                             \
                &smem[32768 + ((BUF) * 2 + bHalf) * 8192 + ((bRdS[n] ^ ((KQ) * 64)) >> 1)]);          \
    }                                                                                                 \
    STAGE_CODE;                                                                                       \
    VMCNT_CODE;                                                                                       \
    asm volatile("" ::: "memory");                                                                    \
    __builtin_amdgcn_s_barrier();                                                                     \
    asm volatile("" ::: "memory");                                                                    \
    __builtin_amdgcn_s_setprio(1);                                                                    \
    _Pragma("unroll")                                                                                 \
    for (int m = 0; m < 4; ++m)                                                                       \
        _Pragma("unroll")                                                                             \
        for (int n = 0; n < 4; ++n)                                                                   \
            acc[(H) * 4 + m][n] =                                                                     \
                __builtin_amdgcn_mfma_f32_16x16x32_bf16(aF[m], bF[KQ][n], acc[(H) * 4 + m][n], 0, 0, 0);\
    __builtin_amdgcn_s_setprio(0);                                                                    \
    asm volatile("" ::: "memory");                                                                    \
    __builtin_amdgcn_s_barrier();                                                                     \
    asm volatile("" ::: "memory");                                                                    \
} while (0)

#define PHH(BUF, H, KQ, LOADB, STAGE_CODE, VMCNT_CODE) do {                                           \
    bf16x8 aFh[2];                                                                                    \
    _Pragma("unroll")                                                                                 \
    for (int m = 0; m < 2; ++m)                                                                       \
        aFh[m] = *reinterpret_cast<const bf16x8*>(                                                    \
            &smem[((BUF) * 2 + (H)) * 8192 + ((aRdH[m] ^ ((KQ) * 64)) >> 1)]);                        \
    if (LOADB) {                                                                                      \
        _Pragma("unroll")                                                                             \
        for (int n = 0; n < 4; ++n)                                                                   \
            bF[KQ][n] = *reinterpret_cast<const bf16x8*>(                                             \
                &smem[32768 + ((BUF) * 2 + bHalf) * 8192 + ((bRdS[n] ^ ((KQ) * 64)) >> 1)]);          \
    }                                                                                                 \
    STAGE_CODE;                                                                                       \
    VMCNT_CODE;                                                                                      \
    asm volatile("" ::: "memory");                                                                    \
    __builtin_amdgcn_s_barrier();                                                                     \
    asm volatile("" ::: "memory");                                                                    \
    __builtin_amdgcn_s_setprio(1);                                                                    \
    _Pragma("unroll")                                                                                 \
    for (int m = 0; m < 2; ++m)                                                                       \
        _Pragma("unroll")                                                                             \
        for (int n = 0; n < 4; ++n)                                                                   \
            acch[(H) * 2 + m][n] =                                                                    \
                __builtin_amdgcn_mfma_f32_16x16x32_bf16(aFh[m], bF[KQ][n], acch[(H) * 2 + m][n], 0, 0, 0);\
    __builtin_amdgcn_s_setprio(0);                                                                    \
    asm volatile("" ::: "memory");                                                                    \
    __builtin_amdgcn_s_barrier();                                                                     \
    asm volatile("" ::: "memory");                                                                    \
} while (0)

#define VMC4 asm volatile("s_waitcnt vmcnt(4)" ::: "memory")
#define VMC3 asm volatile("s_waitcnt vmcnt(3)" ::: "memory")
#define VMC0 asm volatile("s_waitcnt vmcnt(0)" ::: "memory")
#define NOVM (void)0

__global__ __launch_bounds__(512, 2) void gemm_gates8(const unsigned short* __restrict__ A,
                                                      const unsigned short* __restrict__ W,
                                                      const float* __restrict__ bias,
                                                      unsigned short* __restrict__ C) {
    constexpr int K = K_DIM;
    constexpr int NT = K / 64;
    constexpr int NI = NT / 2;
    extern __shared__ unsigned short smem[];

    const int tid = threadIdx.x;
    const int bid = blockIdx.x;                 // 768 blocks: 512 full + 256 half
    const int lane = tid & 63;
    const int wid = tid >> 6;
    const int wr = wid >> 2;
    const int wc = wid & 3;
    const int fr = lane & 15;
    const int kb = lane >> 4;
    const int bHalf = wc >> 1;
    const int swzl = (fr & 7) << 4;

    if (bid < 512) {
        const int swz = (bid & 7) * 64 + (bid >> 3);
        const int tm = swz >> 4;
        const int tn = swz & 15;
        const int Arow0 = tm * 256;
        const int Brow0 = tn * 256;

        int aRdS[4], bRdS[4];
#pragma unroll
        for (int m = 0; m < 4; ++m)
            aRdS[m] = (((wr * 64 + m * 16 + fr) * 128) + kb * 16) ^ swzl;
#pragma unroll
        for (int n = 0; n < 4; ++n)
            bRdS[n] = ((((wc & 1) * 64 + n * 16 + fr) * 128) + kb * 16) ^ swzl;

        size_t aSrc[2], bSrc[2];
        int ldsDst[2];
#pragma unroll
        for (int l = 0; l < 2; ++l) {
            const int off = (l * 512 + tid) * 16;
            const int r = off >> 7;
            const int offS = off ^ ((r & 7) << 4);
            const int cb = (offS & 127) >> 1;
            aSrc[l] = (size_t)(Arow0 + r) * K + cb;
            bSrc[l] = (size_t)(Brow0 + r) * K + cb;
            ldsDst[l] = (l * 512 + tid) * 8;
        }

        auto stageA = [&](int buf, int half, int kt) {
#pragma unroll
            for (int l = 0; l < 2; ++l)
                __builtin_amdgcn_global_load_lds(
                    (cg_void*)(A + aSrc[l] + (size_t)half * 128 * K + kt * 64),
                    (lds_void*)(&smem[(buf * 2 + half) * 8192 + ldsDst[l]]), 16, 0, 0);
        };
        auto stageB = [&](int buf, int half, int kt) {
#pragma unroll
            for (int l = 0; l < 2; ++l)
                __builtin_amdgcn_global_load_lds(
                    (cg_void*)(W + bSrc[l] + (size_t)half * 128 * K + kt * 64),
                    (lds_void*)(&smem[32768 + (buf * 2 + half) * 8192 + ldsDst[l]]), 16, 0, 0);
        };

        f32x4 acc[8][4] = {};

        stageA(0, 0, 0); stageA(0, 1, 0); stageB(0, 0, 0); stageB(0, 1, 0);
        stageB(1, 0, 1); stageB(1, 1, 1);
        VMC4;
        asm volatile("" ::: "memory");
        __builtin_amdgcn_s_barrier();
        asm volatile("" ::: "memory");

        for (int i = 0; i < NI; ++i) {
            const int t1 = 2 * i + 1;
            const int t2 = (2 * i + 2) & (NT - 1);
            const int t3 = (2 * i + 3) & (NT - 1);
            bf16x8 bF[2][4];
            PH(0, 0, 0, 1, { stageA(1, 0, t1); stageA(1, 1, t1); }, NOVM);   // P1
            PH(0, 0, 1, 1, ;, NOVM);                                          // P2
            PH(0, 1, 0, 0, { stageA(0, 0, t2); }, NOVM);                      // P3
            PH(0, 1, 1, 0, { stageB(0, 0, t2); }, VMC4);                      // P4
            PH(1, 0, 0, 1, { stageA(0, 1, t2); stageB(0, 1, t2); }, NOVM);    // P5
            PH(1, 0, 1, 1, ;, NOVM);                                          // P6
            PH(1, 1, 0, 0, { stageB(1, 0, t3); }, NOVM);                      // P7
            PH(1, 1, 1, 0, { stageB(1, 1, t3); }, VMC4);                      // P8
        }

        VMC0;
        asm volatile("" ::: "memory");
        __builtin_amdgcn_s_barrier();
        asm volatile("" ::: "memory");

#pragma unroll
        for (int n = 0; n < 4; ++n) {
            const int lcol = wc * 64 + n * 16 + fr;
            const float bvv = bias[Brow0 + lcol];
#pragma unroll
            for (int hh = 0; hh < 2; ++hh)
#pragma unroll
                for (int m = 0; m < 4; ++m) {
                    const int lr0 = wr * 64 + hh * 128 + m * 16 + kb * 4;
#pragma unroll
                    for (int j = 0; j < 4; ++j) {
                        const int lrow = lr0 + j;
                        const int byte = lrow * 512 + ((lcol * 2) ^ ((lrow & 7) << 4));
                        smem[byte >> 1] = f2bf(acc[hh * 4 + m][n][j] + bvv);
                    }
                }
        }
        asm volatile("" ::: "memory");
        __builtin_amdgcn_s_barrier();
        asm volatile("" ::: "memory");
#pragma unroll
        for (int k = 0; k < 16; ++k) {
            const int cid = k * 512 + tid;
            const int row = cid >> 5;
            const int c16 = cid & 31;
            const int byte = row * 512 + ((c16 * 16) ^ ((row & 7) << 4));
            bf16x8 v = *reinterpret_cast<const bf16x8*>(&smem[byte >> 1]);
            *reinterpret_cast<bf16x8*>(&C[(size_t)(Arow0 + row) * NG + Brow0 + c16 * 8]) = v;
        }
    } else {
        const int idx = bid - 512;
        const int sidx = (idx & 7) * 32 + (idx >> 3);
        const int t2i = sidx >> 1;
        const int mhalf = sidx & 1;
        const int tm = t2i >> 2;
        const int tn = 16 + (t2i & 3);
        const int Arow0 = tm * 256 + mhalf * 128;
        const int Brow0 = tn * 256;

        int aRdH[2], bRdS[4];
#pragma unroll
        for (int m = 0; m < 2; ++m)
            aRdH[m] = (((wr * 32 + m * 16 + fr) * 128) + kb * 16) ^ swzl;
#pragma unroll
        for (int n = 0; n < 4; ++n)
            bRdS[n] = ((((wc & 1) * 64 + n * 16 + fr) * 128) + kb * 16) ^ swzl;

        size_t aSrcH;
        {
            const int off = tid * 16;
            const int r = off >> 7;
            const int offS = off ^ ((r & 7) << 4);
            const int cb = (offS & 127) >> 1;
            aSrcH = (size_t)(Arow0 + r) * K + cb;
        }
        size_t bSrc[2];
        int ldsDst[2];
#pragma unroll
        for (int l = 0; l < 2; ++l) {
            const int off = (l * 512 + tid) * 16;
            const int r = off >> 7;
            const int offS = off ^ ((r & 7) << 4);
            const int cb = (offS & 127) >> 1;
            bSrc[l] = (size_t)(Brow0 + r) * K + cb;
            ldsDst[l] = (l * 512 + tid) * 8;
        }

        auto stageAH = [&](int buf, int half, int kt) {
            __builtin_amdgcn_global_load_lds(
                (cg_void*)(A + aSrcH + (size_t)half * 64 * K + kt * 64),
                (lds_void*)(&smem[(buf * 2 + half) * 8192 + tid * 8]), 16, 0, 0);
        };
        auto stageB = [&](int buf, int half, int kt) {
#pragma unroll
            for (int l = 0; l < 2; ++l)
                __builtin_amdgcn_global_load_lds(
                    (cg_void*)(W + bSrc[l] + (size_t)half * 128 * K + kt * 64),
                    (lds_void*)(&smem[32768 + (buf * 2 + half) * 8192 + ldsDst[l]]), 16, 0, 0);
        };

        f32x4 acch[4][4] = {};

        stageAH(0, 0, 0); stageAH(0, 1, 0); stageB(0, 0, 0); stageB(0, 1, 0);
        stageB(1, 0, 1); stageB(1, 1, 1);
        VMC4;
        asm volatile("" ::: "memory");
        __builtin_amdgcn_s_barrier();
        asm volatile("" ::: "memory");

        for (int i = 0; i < NI; ++i) {
            const int t1 = 2 * i + 1;
            const int t2 = (2 * i + 2) & (NT - 1);
            const int t3 = (2 * i + 3) & (NT - 1);
            bf16x8 bF[2][4];
            PHH(0, 0, 0, 1, { stageAH(1, 0, t1); stageAH(1, 1, t1); }, NOVM);   // P1
            PHH(0, 0, 1, 1, ;, NOVM);                                            // P2
            PHH(0, 1, 0, 0, { stageAH(0, 0, t2); }, NOVM);                       // P3
            PHH(0, 1, 1, 0, { stageB(0, 0, t2); }, VMC3);                        // P4
            PHH(1, 0, 0, 1, { stageAH(0, 1, t2); stageB(0, 1, t2); }, NOVM);     // P5
            PHH(1, 0, 1, 1, ;, NOVM);                                            // P6
            PHH(1, 1, 0, 0, { stageB(1, 0, t3); }, NOVM);                        // P7
            PHH(1, 1, 1, 0, { stageB(1, 1, t3); }, VMC4);                        // P8
        }

        VMC0;
        asm volatile("" ::: "memory");
        __builtin_amdgcn_s_barrier();
        asm volatile("" ::: "memory");

#pragma unroll
        for (int n = 0; n < 4; ++n) {
            const int lcol = wc * 64 + n * 16 + fr;
            const float bvv = bias[Brow0 + lcol];
#pragma unroll
            for (int hh = 0; hh < 2; ++hh)
#pragma unroll
                for (int m = 0; m < 2; ++m) {
                    const int lr0 = hh * 64 + wr * 32 + m * 16 + kb * 4;
#pragma unroll
                    for (int j = 0; j < 4; ++j) {
                        const int lrow = lr0 + j;
                        const int byte = lrow * 512 + ((lcol * 2) ^ ((lrow & 7) << 4));
                        smem[byte >> 1] = f2bf(acch[hh * 2 + m][n][j] + bvv);
                    }
                }
        }
        asm volatile("" ::: "memory");
        __builtin_amdgcn_s_barrier();
        asm volatile("" ::: "memory");
#pragma unroll
        for (int k = 0; k < 8; ++k) {
            const int cid = k * 512 + tid;
            const int row = cid >> 5;
            const int c16 = cid & 31;
            const int byte = row * 512 + ((c16 * 16) ^ ((row & 7) << 4));
            bf16x8 v = *reinterpret_cast<const bf16x8*>(&smem[byte >> 1]);
            *reinterpret_cast<bf16x8*>(&C[(size_t)(Arow0 + row) * NG + Brow0 + c16 * 8]) = v;
        }
    }
}

// ---------------- GEMM2: 128x256 tile, BK=32, 3-slot VMC3 pipeline (R5-verified body),
// 256 blocks (64M x 4N) -> A re-read 4x instead of 8x. Fused epilogue LDS-staged in
// two 128-col chunks (each wave's cols lie fully in one chunk). ----------------
__global__ __launch_bounds__(512, 4) void gemm_out2(const unsigned short* __restrict__ A,   // inp2 [8192][2048]
                                                    const unsigned short* __restrict__ W,   // Wu [1024][2048]
                                                    const float* __restrict__ bias,         // bu [1024]
                                                    const unsigned short* __restrict__ gates,
                                                    const float* __restrict__ x, const float* __restrict__ h,
                                                    float* __restrict__ out) {
    constexpr int K = K_DIM;
    constexpr int NTK = K / 32;                 // 64 K-tiles
    extern __shared__ unsigned short smem[];    // A: 3 x 4096 us [0,12288); B: 3 x 8192 us [12288,36864)

    const int tid = threadIdx.x;
    const int bid = blockIdx.x;                 // 256 blocks (64 M x 4 N), %8==0
    const int swz = (bid & 7) * 32 + (bid >> 3);
    const int tm = swz >> 2;                    // 0..63
    const int tn = swz & 3;                     // 0..3
    const int Arow0 = tm * 128;
    const int Bcol0 = tn * 256;

    const int lane = tid & 63;
    const int wid = tid >> 6;
    const int wr = wid >> 2;        // 0..1 (M)
    const int wc = wid & 3;         // 0..3 (N)
    const int fr = lane & 15;
    const int kb = lane >> 4;

    // ds_read offsets (ushort idx within a slot), R5 swizzle formula
    int aRd[4], bRd[4];
#pragma unroll
    for (int m = 0; m < 4; ++m) {
        const int row = wr * 64 + m * 16 + fr;
        aRd[m] = ((row >> 1) * 128 + ((((row & 1) * 64) + kb * 16) ^ (((row >> 1) & 7) << 4))) >> 1;
    }
#pragma unroll
    for (int n = 0; n < 4; ++n) {
        const int row = wc * 64 + n * 16 + fr;      // W row = output col
        bRd[n] = ((row >> 1) * 128 + ((((row & 1) * 64) + kb * 16) ^ (((row >> 1) & 7) << 4))) >> 1;
    }

    // staging: linear LDS dest, inverse-swizzled global source (R5)
    size_t aSrcB;
    {
        const int line = tid >> 3;
        const int inB = (tid & 7) * 16;
        const int inBS = inB ^ ((line & 7) << 4);
        const int row = line * 2 + (inBS >> 6);
        const int col = (inBS & 63) >> 1;
        aSrcB = (size_t)(Arow0 + row) * K + col;
    }
    size_t bSrcB[2];
#pragma unroll
    for (int l = 0; l < 2; ++l) {
        const int t2 = l * 512 + tid;
        const int line = t2 >> 3;
        const int inB = (t2 & 7) * 16;
        const int inBS = inB ^ ((line & 7) << 4);
        const int row = line * 2 + (inBS >> 6);
        const int col = (inBS & 63) >> 1;
        bSrcB[l] = (size_t)(Bcol0 + row) * K + col;
    }

    auto stageA = [&](int slot, int kt) {
        __builtin_amdgcn_global_load_lds((cg_void*)(A + aSrcB + kt * 32),
                                         (lds_void*)(&smem[slot * 4096 + tid * 8]), 16, 0, 0);
    };
    auto stageB = [&](int slot, int kt) {
#pragma unroll
        for (int l = 0; l < 2; ++l)
            __builtin_amdgcn_global_load_lds((cg_void*)(W + bSrcB[l] + kt * 32),
                                             (lds_void*)(&smem[12288 + slot * 8192 + (l * 512 + tid) * 8]), 16, 0, 0);
    };

    f32x4 acc[4][4] = {};

    // prologue (R5): K-tiles 0,1 into slots 0,1 (6 loads); wait tile0 via vmcnt(3)
    stageA(0, 0); stageB(0, 0);
    stageA(1, 1); stageB(1, 1);
    VMC3;
    asm volatile("" ::: "memory");
    __builtin_amdgcn_s_barrier();
    asm volatile("" ::: "memory");

    int sC = 0;
    for (int t = 0; t < NTK; ++t) {
        const int sP = (sC == 0) ? 2 : sC - 1;
        const int kt2 = (t + 2) & (NTK - 1);

        bf16x8 aF[4], bF[4];
#pragma unroll
        for (int m = 0; m < 4; ++m)
            aF[m] = *reinterpret_cast<const bf16x8*>(&smem[sC * 4096 + aRd[m]]);
#pragma unroll
        for (int n = 0; n < 4; ++n)
            bF[n] = *reinterpret_cast<const bf16x8*>(&smem[12288 + sC * 8192 + bRd[n]]);

        stageA(sP, kt2);
        stageB(sP, kt2);
        VMC3;
        asm volatile("" ::: "memory");
        __builtin_amdgcn_s_barrier();
        asm volatile("" ::: "memory");

        __builtin_amdgcn_s_setprio(1);
#pragma unroll
        for (int m = 0; m < 4; ++m)
#pragma unroll
            for (int n = 0; n < 4; ++n)
                acc[m][n] = __builtin_amdgcn_mfma_f32_16x16x32_bf16(aF[m], bF[n], acc[m][n], 0, 0, 0);
        __builtin_amdgcn_s_setprio(0);
        asm volatile("" ::: "memory");
        __builtin_amdgcn_s_barrier();
        asm volatile("" ::: "memory");

        sC = (sC == 2) ? 0 : sC + 1;
    }

    // drain wrapped in-flight stage loads before smem reuse
    VMC0;
    asm volatile("" ::: "memory");
    __builtin_amdgcn_s_barrier();
    asm volatile("" ::: "memory");

    // fused epilogue, two 128-col chunks; chunk = wc>>1 owns the write pass
    float* fsm = reinterpret_cast<float*>(smem);
#pragma unroll
    for (int chunk = 0; chunk < 2; ++chunk) {
        if ((wc >> 1) == chunk) {
#pragma unroll
            for (int n = 0; n < 4; ++n) {
                const int lcol = wc * 64 + n * 16 + fr;     // 0..255
                const int lcolL = lcol & 127;
                const int c = Bcol0 + lcol;
                const float bvv = bias[c];
#pragma unroll
                for (int m = 0; m < 4; ++m) {
                    const int lr0 = wr * 64 + m * 16 + kb * 4;
#pragma unroll
                    for (int j = 0; j < 4; ++j) {
                        const int lrow = lr0 + j;
                        const size_t r = (size_t)Arow0 + lrow;
                        const float u = tanhf(acc[m][n][j] + bvv);
                        const size_t gb = r * NG + c;
                        const float g2 = bf2f(gates[gb + 2 * D_DIM]);
                        const float g3 = bf2f(gates[gb + 3 * D_DIM]);
                        const float g4 = bf2f(gates[gb + 4 * D_DIM]);
                        const float mx = fmaxf(fmaxf(g2, g3), g4);
                        const float e2 = __expf(g2 - mx), e3 = __expf(g3 - mx), e4 = __expf(g4 - mx);
                        const float zi = 1.0f / (e2 + e3 + e4);
                        const size_t xi = r * D_DIM + c;
                        const float ov = (x[xi] * e2 + h[xi] * e3 + u * e4) * zi;
                        const int dw = lrow * 128 + (lcolL ^ (((lrow >> 2) & 1) << 4));
                        fsm[dw] = ov;
                    }
                }
            }
        }
        asm volatile("" ::: "memory");
        __builtin_amdgcn_s_barrier();
        asm volatile("" ::: "memory");
        // stream chunk: 128 rows x 128 f32 = 4096 float4, 512 threads x 8
#pragma unroll
        for (int k = 0; k < 8; ++k) {
            const int cid = k * 512 + tid;
            const int row = cid >> 5;               // 0..127
            const int c4 = cid & 31;
            const int dw = row * 128 + ((c4 * 4) ^ (((row >> 2) & 1) << 4));
            float4 v = *reinterpret_cast<const float4*>(&fsm[dw]);
            *reinterpret_cast<float4*>(&out[(size_t)(Arow0 + row) * D_DIM + Bcol0 + chunk * 128 + c4 * 4]) = v;
        }
        asm volatile("" ::: "memory");
        __builtin_amdgcn_s_barrier();
        asm volatile("" ::: "memory");
    }
}

extern "C" void kernel_launch(void* const* d_in, const int* in_sizes, int n_in,
                              void* d_out, int out_size, void* d_ws, size_t ws_size,
                              hipStream_t stream) {
    const float* x    = (const float*)d_in[0];
    const float* h    = (const float*)d_in[1];
    const float* ln_w = (const float*)d_in[2];
    const float* ln_b = (const float*)d_in[3];
    const float* ln2_w= (const float*)d_in[4];
    const float* ln2_b= (const float*)d_in[5];
    const float* Wg   = (const float*)d_in[6];
    const float* bg   = (const float*)d_in[7];
    const float* Wu   = (const float*)d_in[8];
    const float* bu   = (const float*)d_in[9];
    float* out = (float*)d_out;

    char* ws = (char*)d_ws;
    unsigned short* inp   = (unsigned short*)(ws);                                   // [8192][2048] (reused as inp2)
    unsigned short* Wg_b  = (unsigned short*)(ws + 33554432);                        // [5120][2048]
    unsigned short* Wu_b  = (unsigned short*)(ws + 33554432 + 20971520);             // [1024][2048]
    unsigned short* gates = (unsigned short*)(ws + 33554432 + 20971520 + 4194304);   // [8192][5120]

    (void)hipFuncSetAttribute((const void*)gemm_gates8,
                              hipFuncAttributeMaxDynamicSharedMemorySize, 131072);
    (void)hipFuncSetAttribute((const void*)gemm_out2,
                              hipFuncAttributeMaxDynamicSharedMemorySize, 73728);

    const int nCvtBlocks = (5120 * 2048 / 4 + 1024 * 2048 / 4 + 255) / 256;   // 12288
    prep_kernel<<<8192 + nCvtBlocks, 256, 0, stream>>>(x, h, ln_w, ln_b, inp, Wg, Wu, Wg_b, Wu_b);
    gemm_gates8<<<768, 512, 131072, stream>>>(inp, Wg_b, bg, gates);
    gate_ln2_kernel<<<8192, 256, 0, stream>>>(x, h, gates, ln2_w, ln2_b, inp);
    gemm_out2<<<256, 512, 73728, stream>>>(inp, Wu_b, bu, gates, x, h, out);
}

// Round 11
// 293.914 us; speedup vs baseline: 1.2959x; 1.2959x over previous
//
#include <hip/hip_runtime.h>

typedef __attribute__((ext_vector_type(8))) __bf16 bf16x8;
typedef __attribute__((ext_vector_type(4))) float f32x4;

#define B_ROWS 8192
#define D_DIM  1024
#define K_DIM  2048
#define NG     5120

typedef const __attribute__((address_space(1))) void cg_void;
typedef __attribute__((address_space(3))) void lds_void;

__device__ __forceinline__ float bf2f(unsigned short u) {
    union { unsigned int ui; float f; } c; c.ui = ((unsigned int)u) << 16; return c.f;
}
__device__ __forceinline__ unsigned short f2bf(float f) {
    unsigned int u = __float_as_uint(f);
    unsigned int r = u + 0x7fffu + ((u >> 16) & 1u);
    return (unsigned short)(r >> 16);
}
__device__ __forceinline__ float sigm(float v) { return 1.0f / (1.0f + __expf(-v)); }

// ---------------- prep: LN1 (blocks 0..8191) + weight cvt (blocks 8192..20479) ----------------
__global__ __launch_bounds__(256) void prep_kernel(const float* __restrict__ x, const float* __restrict__ h,
                                                   const float* __restrict__ w, const float* __restrict__ b,
                                                   unsigned short* __restrict__ outln,
                                                   const float* __restrict__ wg, const float* __restrict__ wu,
                                                   unsigned short* __restrict__ og, unsigned short* __restrict__ ou) {
    const int bid = blockIdx.x;
    const int t = threadIdx.x;
    if (bid < 8192) {
        const int row = bid;
        const float4 xv = reinterpret_cast<const float4*>(x + (size_t)row * D_DIM)[t];
        const float4 hv = reinterpret_cast<const float4*>(h + (size_t)row * D_DIM)[t];
        float s  = xv.x + xv.y + xv.z + xv.w + hv.x + hv.y + hv.z + hv.w;
        float s2 = xv.x*xv.x + xv.y*xv.y + xv.z*xv.z + xv.w*xv.w
                 + hv.x*hv.x + hv.y*hv.y + hv.z*hv.z + hv.w*hv.w;
#pragma unroll
        for (int off = 32; off > 0; off >>= 1) { s += __shfl_xor(s, off); s2 += __shfl_xor(s2, off); }
        __shared__ float red[8];
        const int wid = t >> 6, lane = t & 63;
        if (lane == 0) { red[wid] = s; red[4 + wid] = s2; }
        __syncthreads();
        s  = red[0] + red[1] + red[2] + red[3];
        s2 = red[4] + red[5] + red[6] + red[7];
        const float mu  = s * (1.0f / K_DIM);
        const float var = s2 * (1.0f / K_DIM) - mu * mu;
        const float inv = rsqrtf(var + 1e-5f);
        const float4 w0 = reinterpret_cast<const float4*>(w)[t];
        const float4 b0 = reinterpret_cast<const float4*>(b)[t];
        const float4 w1 = reinterpret_cast<const float4*>(w + D_DIM)[t];
        const float4 b1 = reinterpret_cast<const float4*>(b + D_DIM)[t];
        ushort4 o0, o1;
        o0.x = f2bf((xv.x - mu) * inv * w0.x + b0.x);
        o0.y = f2bf((xv.y - mu) * inv * w0.y + b0.y);
        o0.z = f2bf((xv.z - mu) * inv * w0.z + b0.z);
        o0.w = f2bf((xv.w - mu) * inv * w0.w + b0.w);
        o1.x = f2bf((hv.x - mu) * inv * w1.x + b1.x);
        o1.y = f2bf((hv.y - mu) * inv * w1.y + b1.y);
        o1.z = f2bf((hv.z - mu) * inv * w1.z + b1.z);
        o1.w = f2bf((hv.w - mu) * inv * w1.w + b1.w);
        reinterpret_cast<ushort4*>(outln + (size_t)row * K_DIM)[t] = o0;
        reinterpret_cast<ushort4*>(outln + (size_t)row * K_DIM + D_DIM)[t] = o1;
    } else {
        const int NG4 = 5120 * 2048 / 4;
        const int NU4 = 1024 * 2048 / 4;
        const int i = (bid - 8192) * 256 + t;
        if (i < NG4) {
            float4 v = reinterpret_cast<const float4*>(wg)[i];
            ushort4 o; o.x = f2bf(v.x); o.y = f2bf(v.y); o.z = f2bf(v.z); o.w = f2bf(v.w);
            reinterpret_cast<ushort4*>(og)[i] = o;
        } else if (i < NG4 + NU4) {
            int j = i - NG4;
            float4 v = reinterpret_cast<const float4*>(wu)[j];
            ushort4 o; o.x = f2bf(v.x); o.y = f2bf(v.y); o.z = f2bf(v.z); o.w = f2bf(v.w);
            reinterpret_cast<ushort4*>(ou)[j] = o;
        }
    }
}

// ---------------- gate sigmoid + LN2 -> bf16 inp2 ----------------
__global__ __launch_bounds__(256) void gate_ln2_kernel(const float* __restrict__ x, const float* __restrict__ h,
                                                       const unsigned short* __restrict__ gates,
                                                       const float* __restrict__ w, const float* __restrict__ b,
                                                       unsigned short* __restrict__ out) {
    const int row = blockIdx.x;
    const int t = threadIdx.x;
    const float4 xv = reinterpret_cast<const float4*>(x + (size_t)row * D_DIM)[t];
    const float4 hv = reinterpret_cast<const float4*>(h + (size_t)row * D_DIM)[t];
    const ushort4 g0v = reinterpret_cast<const ushort4*>(gates + (size_t)row * NG)[t];
    const ushort4 g1v = reinterpret_cast<const ushort4*>(gates + (size_t)row * NG + D_DIM)[t];
    float a0 = xv.x * sigm(bf2f(g0v.x));
    float a1 = xv.y * sigm(bf2f(g0v.y));
    float a2 = xv.z * sigm(bf2f(g0v.z));
    float a3 = xv.w * sigm(bf2f(g0v.w));
    float c0 = hv.x * sigm(bf2f(g1v.x));
    float c1 = hv.y * sigm(bf2f(g1v.y));
    float c2 = hv.z * sigm(bf2f(g1v.z));
    float c3 = hv.w * sigm(bf2f(g1v.w));
    float s  = a0 + a1 + a2 + a3 + c0 + c1 + c2 + c3;
    float s2 = a0*a0 + a1*a1 + a2*a2 + a3*a3 + c0*c0 + c1*c1 + c2*c2 + c3*c3;
#pragma unroll
    for (int off = 32; off > 0; off >>= 1) { s += __shfl_xor(s, off); s2 += __shfl_xor(s2, off); }
    __shared__ float red[8];
    const int wid = t >> 6, lane = t & 63;
    if (lane == 0) { red[wid] = s; red[4 + wid] = s2; }
    __syncthreads();
    s  = red[0] + red[1] + red[2] + red[3];
    s2 = red[4] + red[5] + red[6] + red[7];
    const float mu  = s * (1.0f / K_DIM);
    const float var = s2 * (1.0f / K_DIM) - mu * mu;
    const float inv = rsqrtf(var + 1e-5f);
    const float4 w0 = reinterpret_cast<const float4*>(w)[t];
    const float4 b0 = reinterpret_cast<const float4*>(b)[t];
    const float4 w1 = reinterpret_cast<const float4*>(w + D_DIM)[t];
    const float4 b1 = reinterpret_cast<const float4*>(b + D_DIM)[t];
    ushort4 o0, o1;
    o0.x = f2bf((a0 - mu) * inv * w0.x + b0.x);
    o0.y = f2bf((a1 - mu) * inv * w0.y + b0.y);
    o0.z = f2bf((a2 - mu) * inv * w0.z + b0.z);
    o0.w = f2bf((a3 - mu) * inv * w0.w + b0.w);
    o1.x = f2bf((c0 - mu) * inv * w1.x + b1.x);
    o1.y = f2bf((c1 - mu) * inv * w1.y + b1.y);
    o1.z = f2bf((c2 - mu) * inv * w1.z + b1.z);
    o1.w = f2bf((c3 - mu) * inv * w1.w + b1.w);
    reinterpret_cast<ushort4*>(out + (size_t)row * K_DIM)[t] = o0;
    reinterpret_cast<ushort4*>(out + (size_t)row * K_DIM + D_DIM)[t] = o1;
}

// ---------------- GEMM1: uniform-round grid (768 blocks), R8-verified ----------------
#define PH(BUF, H, KQ, LOADB, STAGE_CODE, VMCNT_CODE) do {                                            \
    bf16x8 aF[4];                                                                                     \
    _Pragma("unroll")                                                                                 \
    for (int m = 0; m < 4; ++m)                                                                       \
        aF[m] = *reinterpret_cast<const bf16x8*>(                                                     \
            &smem[((BUF) * 2 + (H)) * 8192 + ((aRdS[m] ^ ((KQ) * 64)) >> 1)]);                        \
    if (LOADB) {                                                                                      \
        _Pragma("unroll")                                                                             \
        for (int n = 0; n < 4; ++n)                                                                   \
            bF[KQ][n] = *reinterpret_cast<const bf16x8*>(                                             \
                &smem[32768 + ((BUF) * 2 + bHalf) * 8192 + ((bRdS[n] ^ ((KQ) * 64)) >> 1)]);          \
    }                                                                                                 \
    STAGE_CODE;                                                                                       \
    VMCNT_CODE;                                                                                       \
    asm volatile("" ::: "memory");                                                                    \
    __builtin_amdgcn_s_barrier();                                                                     \
    asm volatile("" ::: "memory");                                                                    \
    __builtin_amdgcn_s_setprio(1);                                                                    \
    _Pragma("unroll")                                                                                 \
    for (int m = 0; m < 4; ++m)                                                                       \
        _Pragma("unroll")                                                                             \
        for (int n = 0; n < 4; ++n)                                                                   \
            acc[(H) * 4 + m][n] =                                                                     \
                __builtin_amdgcn_mfma_f32_16x16x32_bf16(aF[m], bF[KQ][n], acc[(H) * 4 + m][n], 0, 0, 0);\
    __builtin_amdgcn_s_setprio(0);                                                                    \
    asm volatile("" ::: "memory");                                                                    \
    __builtin_amdgcn_s_barrier();                                                                     \
    asm volatile("" ::: "memory");                                                                    \
} while (0)

#define PHH(BUF, H, KQ, LOADB, STAGE_CODE, VMCNT_CODE) do {                                           \
    bf16x8 aFh[2];                                                                                    \
    _Pragma("unroll")                                                                                 \
    for (int m = 0; m < 2; ++m)                                                                       \
        aFh[m] = *reinterpret_cast<const bf16x8*>(                                                    \
            &smem[((BUF) * 2 + (H)) * 8192 + ((aRdH[m] ^ ((KQ) * 64)) >> 1)]);                        \
    if (LOADB) {                                                                                      \
        _Pragma("unroll")                                                                             \
        for (int n = 0; n < 4; ++n)                                                                   \
            bF[KQ][n] = *reinterpret_cast<const bf16x8*>(                                             \
                &smem[32768 + ((BUF) * 2 + bHalf) * 8192 + ((bRdS[n] ^ ((KQ) * 64)) >> 1)]);          \
    }                                                                                                 \
    STAGE_CODE;                                                                                       \
    VMCNT_CODE;                                                                                      \
    asm volatile("" ::: "memory");                                                                    \
    __builtin_amdgcn_s_barrier();                                                                     \
    asm volatile("" ::: "memory");                                                                    \
    __builtin_amdgcn_s_setprio(1);                                                                    \
    _Pragma("unroll")                                                                                 \
    for (int m = 0; m < 2; ++m)                                                                       \
        _Pragma("unroll")                                                                             \
        for (int n = 0; n < 4; ++n)                                                                   \
            acch[(H) * 2 + m][n] =                                                                    \
                __builtin_amdgcn_mfma_f32_16x16x32_bf16(aFh[m], bF[KQ][n], acch[(H) * 2 + m][n], 0, 0, 0);\
    __builtin_amdgcn_s_setprio(0);                                                                    \
    asm volatile("" ::: "memory");                                                                    \
    __builtin_amdgcn_s_barrier();                                                                     \
    asm volatile("" ::: "memory");                                                                    \
} while (0)

#define VMC4 asm volatile("s_waitcnt vmcnt(4)" ::: "memory")
#define VMC3 asm volatile("s_waitcnt vmcnt(3)" ::: "memory")
#define VMC0 asm volatile("s_waitcnt vmcnt(0)" ::: "memory")
#define NOVM (void)0

__global__ __launch_bounds__(512, 2) void gemm_gates8(const unsigned short* __restrict__ A,
                                                      const unsigned short* __restrict__ W,
                                                      const float* __restrict__ bias,
                                                      unsigned short* __restrict__ C) {
    constexpr int K = K_DIM;
    constexpr int NT = K / 64;
    constexpr int NI = NT / 2;
    extern __shared__ unsigned short smem[];

    const int tid = threadIdx.x;
    const int bid = blockIdx.x;                 // 768 blocks: 512 full + 256 half
    const int lane = tid & 63;
    const int wid = tid >> 6;
    const int wr = wid >> 2;
    const int wc = wid & 3;
    const int fr = lane & 15;
    const int kb = lane >> 4;
    const int bHalf = wc >> 1;
    const int swzl = (fr & 7) << 4;

    if (bid < 512) {
        const int swz = (bid & 7) * 64 + (bid >> 3);
        const int tm = swz >> 4;
        const int tn = swz & 15;
        const int Arow0 = tm * 256;
        const int Brow0 = tn * 256;

        int aRdS[4], bRdS[4];
#pragma unroll
        for (int m = 0; m < 4; ++m)
            aRdS[m] = (((wr * 64 + m * 16 + fr) * 128) + kb * 16) ^ swzl;
#pragma unroll
        for (int n = 0; n < 4; ++n)
            bRdS[n] = ((((wc & 1) * 64 + n * 16 + fr) * 128) + kb * 16) ^ swzl;

        size_t aSrc[2], bSrc[2];
        int ldsDst[2];
#pragma unroll
        for (int l = 0; l < 2; ++l) {
            const int off = (l * 512 + tid) * 16;
            const int r = off >> 7;
            const int offS = off ^ ((r & 7) << 4);
            const int cb = (offS & 127) >> 1;
            aSrc[l] = (size_t)(Arow0 + r) * K + cb;
            bSrc[l] = (size_t)(Brow0 + r) * K + cb;
            ldsDst[l] = (l * 512 + tid) * 8;
        }

        auto stageA = [&](int buf, int half, int kt) {
#pragma unroll
            for (int l = 0; l < 2; ++l)
                __builtin_amdgcn_global_load_lds(
                    (cg_void*)(A + aSrc[l] + (size_t)half * 128 * K + kt * 64),
                    (lds_void*)(&smem[(buf * 2 + half) * 8192 + ldsDst[l]]), 16, 0, 0);
        };
        auto stageB = [&](int buf, int half, int kt) {
#pragma unroll
            for (int l = 0; l < 2; ++l)
                __builtin_amdgcn_global_load_lds(
                    (cg_void*)(W + bSrc[l] + (size_t)half * 128 * K + kt * 64),
                    (lds_void*)(&smem[32768 + (buf * 2 + half) * 8192 + ldsDst[l]]), 16, 0, 0);
        };

        f32x4 acc[8][4] = {};

        stageA(0, 0, 0); stageA(0, 1, 0); stageB(0, 0, 0); stageB(0, 1, 0);
        stageB(1, 0, 1); stageB(1, 1, 1);
        VMC4;
        asm volatile("" ::: "memory");
        __builtin_amdgcn_s_barrier();
        asm volatile("" ::: "memory");

        for (int i = 0; i < NI; ++i) {
            const int t1 = 2 * i + 1;
            const int t2 = (2 * i + 2) & (NT - 1);
            const int t3 = (2 * i + 3) & (NT - 1);
            bf16x8 bF[2][4];
            PH(0, 0, 0, 1, { stageA(1, 0, t1); stageA(1, 1, t1); }, NOVM);   // P1
            PH(0, 0, 1, 1, ;, NOVM);                                          // P2
            PH(0, 1, 0, 0, { stageA(0, 0, t2); }, NOVM);                      // P3
            PH(0, 1, 1, 0, { stageB(0, 0, t2); }, VMC4);                      // P4
            PH(1, 0, 0, 1, { stageA(0, 1, t2); stageB(0, 1, t2); }, NOVM);    // P5
            PH(1, 0, 1, 1, ;, NOVM);                                          // P6
            PH(1, 1, 0, 0, { stageB(1, 0, t3); }, NOVM);                      // P7
            PH(1, 1, 1, 0, { stageB(1, 1, t3); }, VMC4);                      // P8
        }

        VMC0;
        asm volatile("" ::: "memory");
        __builtin_amdgcn_s_barrier();
        asm volatile("" ::: "memory");

#pragma unroll
        for (int n = 0; n < 4; ++n) {
            const int lcol = wc * 64 + n * 16 + fr;
            const float bvv = bias[Brow0 + lcol];
#pragma unroll
            for (int hh = 0; hh < 2; ++hh)
#pragma unroll
                for (int m = 0; m < 4; ++m) {
                    const int lr0 = wr * 64 + hh * 128 + m * 16 + kb * 4;
#pragma unroll
                    for (int j = 0; j < 4; ++j) {
                        const int lrow = lr0 + j;
                        const int byte = lrow * 512 + ((lcol * 2) ^ ((lrow & 7) << 4));
                        smem[byte >> 1] = f2bf(acc[hh * 4 + m][n][j] + bvv);
                    }
                }
        }
        asm volatile("" ::: "memory");
        __builtin_amdgcn_s_barrier();
        asm volatile("" ::: "memory");
#pragma unroll
        for (int k = 0; k < 16; ++k) {
            const int cid = k * 512 + tid;
            const int row = cid >> 5;
            const int c16 = cid & 31;
            const int byte = row * 512 + ((c16 * 16) ^ ((row & 7) << 4));
            bf16x8 v = *reinterpret_cast<const bf16x8*>(&smem[byte >> 1]);
            *reinterpret_cast<bf16x8*>(&C[(size_t)(Arow0 + row) * NG + Brow0 + c16 * 8]) = v;
        }
    } else {
        const int idx = bid - 512;
        const int sidx = (idx & 7) * 32 + (idx >> 3);
        const int t2i = sidx >> 1;
        const int mhalf = sidx & 1;
        const int tm = t2i >> 2;
        const int tn = 16 + (t2i & 3);
        const int Arow0 = tm * 256 + mhalf * 128;
        const int Brow0 = tn * 256;

        int aRdH[2], bRdS[4];
#pragma unroll
        for (int m = 0; m < 2; ++m)
            aRdH[m] = (((wr * 32 + m * 16 + fr) * 128) + kb * 16) ^ swzl;
#pragma unroll
        for (int n = 0; n < 4; ++n)
            bRdS[n] = ((((wc & 1) * 64 + n * 16 + fr) * 128) + kb * 16) ^ swzl;

        size_t aSrcH;
        {
            const int off = tid * 16;
            const int r = off >> 7;
            const int offS = off ^ ((r & 7) << 4);
            const int cb = (offS & 127) >> 1;
            aSrcH = (size_t)(Arow0 + r) * K + cb;
        }
        size_t bSrc[2];
        int ldsDst[2];
#pragma unroll
        for (int l = 0; l < 2; ++l) {
            const int off = (l * 512 + tid) * 16;
            const int r = off >> 7;
            const int offS = off ^ ((r & 7) << 4);
            const int cb = (offS & 127) >> 1;
            bSrc[l] = (size_t)(Brow0 + r) * K + cb;
            ldsDst[l] = (l * 512 + tid) * 8;
        }

        auto stageAH = [&](int buf, int half, int kt) {
            __builtin_amdgcn_global_load_lds(
                (cg_void*)(A + aSrcH + (size_t)half * 64 * K + kt * 64),
                (lds_void*)(&smem[(buf * 2 + half) * 8192 + tid * 8]), 16, 0, 0);
        };
        auto stageB = [&](int buf, int half, int kt) {
#pragma unroll
            for (int l = 0; l < 2; ++l)
                __builtin_amdgcn_global_load_lds(
                    (cg_void*)(W + bSrc[l] + (size_t)half * 128 * K + kt * 64),
                    (lds_void*)(&smem[32768 + (buf * 2 + half) * 8192 + ldsDst[l]]), 16, 0, 0);
        };

        f32x4 acch[4][4] = {};

        stageAH(0, 0, 0); stageAH(0, 1, 0); stageB(0, 0, 0); stageB(0, 1, 0);
        stageB(1, 0, 1); stageB(1, 1, 1);
        VMC4;
        asm volatile("" ::: "memory");
        __builtin_amdgcn_s_barrier();
        asm volatile("" ::: "memory");

        for (int i = 0; i < NI; ++i) {
            const int t1 = 2 * i + 1;
            const int t2 = (2 * i + 2) & (NT - 1);
            const int t3 = (2 * i + 3) & (NT - 1);
            bf16x8 bF[2][4];
            PHH(0, 0, 0, 1, { stageAH(1, 0, t1); stageAH(1, 1, t1); }, NOVM);   // P1
            PHH(0, 0, 1, 1, ;, NOVM);                                            // P2
            PHH(0, 1, 0, 0, { stageAH(0, 0, t2); }, NOVM);                       // P3
            PHH(0, 1, 1, 0, { stageB(0, 0, t2); }, VMC3);                        // P4
            PHH(1, 0, 0, 1, { stageAH(0, 1, t2); stageB(0, 1, t2); }, NOVM);     // P5
            PHH(1, 0, 1, 1, ;, NOVM);                                            // P6
            PHH(1, 1, 0, 0, { stageB(1, 0, t3); }, NOVM);                        // P7
            PHH(1, 1, 1, 0, { stageB(1, 1, t3); }, VMC4);                        // P8
        }

        VMC0;
        asm volatile("" ::: "memory");
        __builtin_amdgcn_s_barrier();
        asm volatile("" ::: "memory");

#pragma unroll
        for (int n = 0; n < 4; ++n) {
            const int lcol = wc * 64 + n * 16 + fr;
            const float bvv = bias[Brow0 + lcol];
#pragma unroll
            for (int hh = 0; hh < 2; ++hh)
#pragma unroll
                for (int m = 0; m < 2; ++m) {
                    const int lr0 = hh * 64 + wr * 32 + m * 16 + kb * 4;
#pragma unroll
                    for (int j = 0; j < 4; ++j) {
                        const int lrow = lr0 + j;
                        const int byte = lrow * 512 + ((lcol * 2) ^ ((lrow & 7) << 4));
                        smem[byte >> 1] = f2bf(acch[hh * 2 + m][n][j] + bvv);
                    }
                }
        }
        asm volatile("" ::: "memory");
        __builtin_amdgcn_s_barrier();
        asm volatile("" ::: "memory");
#pragma unroll
        for (int k = 0; k < 8; ++k) {
            const int cid = k * 512 + tid;
            const int row = cid >> 5;
            const int c16 = cid & 31;
            const int byte = row * 512 + ((c16 * 16) ^ ((row & 7) << 4));
            bf16x8 v = *reinterpret_cast<const bf16x8*>(&smem[byte >> 1]);
            *reinterpret_cast<bf16x8*>(&C[(size_t)(Arow0 + row) * NG + Brow0 + c16 * 8]) = v;
        }
    }
}

// ---------------- GEMM2: 128x128, 3-slot counted-vmcnt pipeline (R6/R8/R9-verified),
// 512 blocks (2-3/CU co-resident), LDS-staged f32 epilogue ----------------
__global__ __launch_bounds__(256, 3) void gemm_out3(const unsigned short* __restrict__ A,
                                                    const unsigned short* __restrict__ W,
                                                    const float* __restrict__ bias,
                                                    const unsigned short* __restrict__ gates,
                                                    const float* __restrict__ x, const float* __restrict__ h,
                                                    float* __restrict__ out) {
    constexpr int K = K_DIM;
    constexpr int NTK = K / 32;
    extern __shared__ unsigned short smem[];

    const int tid = threadIdx.x;
    const int bid = blockIdx.x;
    const int swz = (bid & 7) * 64 + (bid >> 3);
    const int tn = swz & 7;
    const int tm = swz >> 3;
    const int Arow0 = tm * 128;
    const int Brow0 = tn * 128;

    const int lane = tid & 63;
    const int wid = tid >> 6;
    const int wr = wid >> 1;
    const int wc = wid & 1;
    const int fr = lane & 15;
    const int kb = lane >> 4;

    int aRd[4], bRd[4];
#pragma unroll
    for (int m = 0; m < 4; ++m) {
        const int row = wr * 64 + m * 16 + fr;
        aRd[m] = ((row >> 1) * 128 + ((((row & 1) * 64) + kb * 16) ^ (((row >> 1) & 7) << 4))) >> 1;
    }
#pragma unroll
    for (int n = 0; n < 4; ++n) {
        const int row = wc * 64 + n * 16 + fr;
        bRd[n] = ((row >> 1) * 128 + ((((row & 1) * 64) + kb * 16) ^ (((row >> 1) & 7) << 4))) >> 1;
    }

    size_t aSrcB[2], bSrcB[2];
#pragma unroll
    for (int l = 0; l < 2; ++l) {
        const int t2 = l * 256 + tid;
        const int line = t2 >> 3;
        const int inB = (t2 & 7) * 16;
        const int inBS = inB ^ ((line & 7) << 4);
        const int row = line * 2 + (inBS >> 6);
        const int col = (inBS & 63) >> 1;
        aSrcB[l] = (size_t)(Arow0 + row) * K + col;
        bSrcB[l] = (size_t)(Brow0 + row) * K + col;
    }

    auto stage = [&](int slot, int kt) {
#pragma unroll
        for (int l = 0; l < 2; ++l)
            __builtin_amdgcn_global_load_lds((cg_void*)(A + aSrcB[l] + kt * 32),
                                             (lds_void*)(&smem[slot * 4096 + (l * 256 + tid) * 8]), 16, 0, 0);
#pragma unroll
        for (int l = 0; l < 2; ++l)
            __builtin_amdgcn_global_load_lds((cg_void*)(W + bSrcB[l] + kt * 32),
                                             (lds_void*)(&smem[12288 + slot * 4096 + (l * 256 + tid) * 8]), 16, 0, 0);
    };

    f32x4 acc[4][4] = {};

    stage(0, 0); stage(1, 1);
    VMC4;
    asm volatile("" ::: "memory");
    __builtin_amdgcn_s_barrier();
    asm volatile("" ::: "memory");

    int sC = 0;
    for (int t = 0; t < NTK; ++t) {
        const int sP = (sC == 0) ? 2 : sC - 1;
        const int kt2 = (t + 2) & (NTK - 1);

        bf16x8 aF[4], bF[4];
#pragma unroll
        for (int m = 0; m < 4; ++m)
            aF[m] = *reinterpret_cast<const bf16x8*>(&smem[sC * 4096 + aRd[m]]);
#pragma unroll
        for (int n = 0; n < 4; ++n)
            bF[n] = *reinterpret_cast<const bf16x8*>(&smem[12288 + sC * 4096 + bRd[n]]);

        stage(sP, kt2);
        VMC4;
        asm volatile("" ::: "memory");
        __builtin_amdgcn_s_barrier();
        asm volatile("" ::: "memory");

        __builtin_amdgcn_s_setprio(1);
#pragma unroll
        for (int m = 0; m < 4; ++m)
#pragma unroll
            for (int n = 0; n < 4; ++n)
                acc[m][n] = __builtin_amdgcn_mfma_f32_16x16x32_bf16(aF[m], bF[n], acc[m][n], 0, 0, 0);
        __builtin_amdgcn_s_setprio(0);
        asm volatile("" ::: "memory");
        __builtin_amdgcn_s_barrier();
        asm volatile("" ::: "memory");

        sC = (sC == 2) ? 0 : sC + 1;
    }

    VMC0;
    asm volatile("" ::: "memory");
    __builtin_amdgcn_s_barrier();
    asm volatile("" ::: "memory");

    float* fsm = reinterpret_cast<float*>(smem);
#pragma unroll
    for (int n = 0; n < 4; ++n) {
        const int lcol = wc * 64 + n * 16 + fr;
        const int c = Brow0 + lcol;
        const float bvv = bias[c];
#pragma unroll
        for (int m = 0; m < 4; ++m) {
            const int lr0 = wr * 64 + m * 16 + kb * 4;
#pragma unroll
            for (int j = 0; j < 4; ++j) {
                const int lrow = lr0 + j;
                const size_t r = (size_t)Arow0 + lrow;
                const float u = tanhf(acc[m][n][j] + bvv);
                const size_t gb = r * NG + c;
                const float g2 = bf2f(gates[gb + 2 * D_DIM]);
                const float g3 = bf2f(gates[gb + 3 * D_DIM]);
                const float g4 = bf2f(gates[gb + 4 * D_DIM]);
                const float mx = fmaxf(fmaxf(g2, g3), g4);
                const float e2 = __expf(g2 - mx), e3 = __expf(g3 - mx), e4 = __expf(g4 - mx);
                const float zi = 1.0f / (e2 + e3 + e4);
                const size_t xi = r * D_DIM + c;
                const float ov = (x[xi] * e2 + h[xi] * e3 + u * e4) * zi;
                const int dw = lrow * 128 + (lcol ^ (((lrow >> 2) & 1) << 4));
                fsm[dw] = ov;
            }
        }
    }
    asm volatile("" ::: "memory");
    __builtin_amdgcn_s_barrier();
    asm volatile("" ::: "memory");

#pragma unroll
    for (int k = 0; k < 16; ++k) {
        const int cid = k * 256 + tid;
        const int row = cid >> 5;
        const int c4 = cid & 31;
        const int dw = row * 128 + ((c4 * 4) ^ (((row >> 2) & 1) << 4));
        float4 v = *reinterpret_cast<const float4*>(&fsm[dw]);
        *reinterpret_cast<float4*>(&out[(size_t)(Arow0 + row) * D_DIM + Brow0 + c4 * 4]) = v;
    }
}

extern "C" void kernel_launch(void* const* d_in, const int* in_sizes, int n_in,
                              void* d_out, int out_size, void* d_ws, size_t ws_size,
                              hipStream_t stream) {
    const float* x    = (const float*)d_in[0];
    const float* h    = (const float*)d_in[1];
    const float* ln_w = (const float*)d_in[2];
    const float* ln_b = (const float*)d_in[3];
    const float* ln2_w= (const float*)d_in[4];
    const float* ln2_b= (const float*)d_in[5];
    const float* Wg   = (const float*)d_in[6];
    const float* bg   = (const float*)d_in[7];
    const float* Wu   = (const float*)d_in[8];
    const float* bu   = (const float*)d_in[9];
    float* out = (float*)d_out;

    char* ws = (char*)d_ws;
    unsigned short* inp   = (unsigned short*)(ws);                                   // [8192][2048] (reused as inp2)
    unsigned short* Wg_b  = (unsigned short*)(ws + 33554432);                        // [5120][2048]
    unsigned short* Wu_b  = (unsigned short*)(ws + 33554432 + 20971520);             // [1024][2048]
    unsigned short* gates = (unsigned short*)(ws + 33554432 + 20971520 + 4194304);   // [8192][5120]

    (void)hipFuncSetAttribute((const void*)gemm_gates8,
                              hipFuncAttributeMaxDynamicSharedMemorySize, 131072);
    (void)hipFuncSetAttribute((const void*)gemm_out3,
                              hipFuncAttributeMaxDynamicSharedMemorySize, 65536);

    const int nCvtBlocks = (5120 * 2048 / 4 + 1024 * 2048 / 4 + 255) / 256;   // 12288
    prep_kernel<<<8192 + nCvtBlocks, 256, 0, stream>>>(x, h, ln_w, ln_b, inp, Wg, Wu, Wg_b, Wu_b);
    gemm_gates8<<<768, 512, 131072, stream>>>(inp, Wg_b, bg, gates);
    gate_ln2_kernel<<<8192, 256, 0, stream>>>(x, h, gates, ln2_w, ln2_b, inp);
    gemm_out3<<<512, 256, 65536, stream>>>(inp, Wu_b, bu, gates, x, h, out);
}